// Round 11
// baseline (190.510 us; speedup 1.0000x reference)
//
#include <hip/hip_runtime.h>
#include <stdint.h>

#define N_Q   65536
#define N_S   65536
#define NB_H  26
#define PAD_H 28
#define KP    10
#define CIN   64
#define COUT  128
#define MT    16   // query points per block
#define BM    16   // output rows per block

typedef unsigned short u16x8  __attribute__((ext_vector_type(8)));
typedef float          f32x4  __attribute__((ext_vector_type(4)));
typedef float          f32x2  __attribute__((ext_vector_type(2)));
typedef _Float16       f16x8  __attribute__((ext_vector_type(8)));
typedef _Float16       f16x2  __attribute__((ext_vector_type(2)));
typedef unsigned int   u32x4  __attribute__((ext_vector_type(4)));
typedef unsigned int   u32x2  __attribute__((ext_vector_type(2)));

#define PACK_BLOCKS 40    // ceil(8*20*64 / 256)

static __device__ __forceinline__ unsigned short f2h(float f) {
  return __builtin_bit_cast(unsigned short, (_Float16)f);   // RTN, matches old prep
}

// v_cvt_pkrtz_f16_f32 packed to raw u32 (weights path only, as in all rounds)
static __device__ __forceinline__ unsigned int pkrtz_u32(float a, float b) {
  return __builtin_bit_cast(unsigned int, __builtin_amdgcn_cvt_pkrtz(a, b));
}

// pack two RTN-converted halves into one u32 half2
static __device__ __forceinline__ unsigned int packh2(float lo, float hi) {
  return (unsigned int)f2h(lo) | ((unsigned int)f2h(hi) << 16);
}

// half2-dot with fp32 accumulate: v_dot2_f32_f16
static __device__ __forceinline__ float fdot2u(unsigned int a, unsigned int b, float c) {
#if __has_builtin(__builtin_amdgcn_fdot2)
  return __builtin_amdgcn_fdot2(__builtin_bit_cast(f16x2, a),
                                __builtin_bit_cast(f16x2, b), c, false);
#else
  f16x2 ha = __builtin_bit_cast(f16x2, a), hb = __builtin_bit_cast(f16x2, b);
  return c + (float)ha[0] * (float)hb[0] + (float)ha[1] * (float)hb[1];
#endif
}

// ---- prep: weight pack ONLY (x conversion pass deleted this round) ----------
// Bpack[((ct*20 + ks)*64 + lane)*8 + j] = B[ks*32 + (lane>>4)*8 + j][ct*16 + (lane&15)]
__global__ void prep_kernel(const float* __restrict__ w,
                            unsigned short* __restrict__ bp) {
  int t = blockIdx.x * blockDim.x + threadIdx.x;
  if (t >= 8 * 20 * 64) return;
  int lane = t & 63;
  int frag = t >> 6;            // ct*20 + ks
  int ks = frag % 20;
  int ct = frag / 20;
  int row0 = ks * 32 + (lane >> 4) * 8;
  int col  = ct * 16 + (lane & 15);
  u16x8 o;
  #pragma unroll
  for (int j = 0; j < 8; ++j) o[j] = f2h(w[(row0 + j) * COUT + col]);
  *(u16x8*)(bp + (long)t * 8) = o;
}

// ---- fused kernel: R9 structure + DIRECT fp32 x gather (no xh pre-pass) -----
// R10 lesson: dur is independent of FETCH volume (79MB vs 39.5MB, same 93-96us)
// -> the fused kernel sits at a balanced multi-pipe floor. The unexamined cost
// is the ~72us residual (dur_us 167 - fused 93); prep has never been visible in
// top-5 (cutoff ~93us) and could be most of it. This round makes prep trivially
// small (40 blocks) by gathering x fp32 directly in phase C: f32x2 loads
// (coalescing unchanged: 512B/wave-instr), f2h RTN pairs at use -> numerics
// bit-identical to R9. Shadow ind==N_S clamps to row 0: its weights are exactly
// 0.0 (fmax at 1e6 distance), so 0*finite = 0 -- exact.
//
// LDS layout (smem, 32256 B):
//   [    0, 20480) sA (20 frags x 512 halves, XOR swz); before post-B barrier
//                  first 7040 B double as nbr[16][80] | kp[16][30]
//   [20480, 30464) aw[16][13][12] u32
//   [30464, 32256) offx[16][28] u32 (byte offsets into x, 2 pad/row for b128)
#define NBR(m, c)    (((float*)smem)[(m) * 80 + (c)])
#define KPQ(m, r)    (((float*)(smem + 5120))[(m) * 30 + (r)])
#define AW(m, hp, k) (((unsigned int*)(smem + 20480))[((m) * 13 + (hp)) * 12 + (k)])
#define OFFX(m, h)   (((unsigned int*)(smem + 30464))[(m) * 28 + (h)])

__global__ void __launch_bounds__(512, 5)   // cap ~102 VGPR: fp32 window needs
kpconv_fused(const float* __restrict__ q_pts, const float* __restrict__ s_pts, // headroom, never squeeze (R6)
             const float* __restrict__ gen_W, const float* __restrict__ gen_b,
             const int* __restrict__ inds, const float* __restrict__ x,
             const unsigned short* __restrict__ bp, float* __restrict__ out) {

  __shared__ char smem[32256] __attribute__((aligned(16)));
  unsigned short* sA = (unsigned short*)smem;
  const char* xb = (const char*)x;

  const int  tid  = threadIdx.x;
  const int  lane = tid & 63;
  const int  wv   = tid >> 6;                        // 0..7
  const int  m0   = wv * 2;                          // wave-owned rows m0, m0+1
  const long row0 = (long)blockIdx.x * BM;

  // ---- Phase A (per-wave, 1 iter): neighbors = s_pad[ind] - q ----
  if (lane < 2 * NB_H) {
    int m = m0 + lane / NB_H;
    int h = lane % NB_H;
    int n = (int)row0 + m;
    int ind = inds[n * NB_H + h];
    // clamp shadow (ind==N_S) to row 0: its weights are exactly 0 -> exact
    OFFX(m, h) = (unsigned)((unsigned)ind < (unsigned)N_S ? ind : 0) << 8;
    float sx, sy, sz;
    if ((unsigned)ind < (unsigned)N_S) {
      sx = s_pts[ind * 3 + 0]; sy = s_pts[ind * 3 + 1]; sz = s_pts[ind * 3 + 2];
    } else {
      sx = 1e6f; sy = 1e6f; sz = 1e6f;   // shadow support point
    }
    NBR(m, h * 3 + 0) = sx - q_pts[n * 3 + 0];
    NBR(m, h * 3 + 1) = sy - q_pts[n * 3 + 1];
    NBR(m, h * 3 + 2) = sz - q_pts[n * 3 + 2];
  }
  if (lane < 4) NBR(m0 + (lane >> 1), 78 + (lane & 1)) = -1.0f;
  asm volatile("s_waitcnt lgkmcnt(0)" ::: "memory");   // wave-local fence

  // ---- Hoist ALL 26 gather offsets into VGPRs (7 x b128 LDS reads) ----
  const int il   = lane & 31;
  const int g2   = lane >> 5;
  const int i0   = il * 2;
  const int rowc = m0 + g2;                          // this thread's row
  unsigned int voff[26];
  {
    const unsigned int cb = (unsigned)i0 * 4;        // channel byte offset (fp32)
    u32x4 t[7];
    #pragma unroll
    for (int q = 0; q < 7; ++q) t[q] = *(const u32x4*)&OFFX(rowc, q * 4);
    #pragma unroll
    for (int h = 0; h < 26; ++h) voff[h] = t[h >> 2][h & 3] + cb;
  }

  // ---- Window prefetch h=0..12 (13 f32x2 in flight; lands during A2+B) ----
  f32x2 win[13];
  #pragma unroll
  for (int h = 0; h < 13; ++h)
    win[h] = *(const f32x2*)(xb + voff[h]);

  // ---- Phase A2 (per-wave, 1 iter): kp = padded @ gen_W^T + gen_b ----
  if (lane < 2 * 30) {
    int m = m0 + lane / 30;
    int r = lane % 30;
    const float* Wr = gen_W + r * (PAD_H * 3);
    const f32x4* W4 = (const f32x4*)Wr;
    const f32x4* N4 = (const f32x4*)&NBR(m, 0);
    f32x4 accv = {0.f, 0.f, 0.f, 0.f};
    #pragma unroll
    for (int j = 0; j < 20; ++j) accv += W4[j] * N4[j];
    KPQ(m, r) = gen_b[r] - (Wr[80] + Wr[81] + Wr[82] + Wr[83])
              + accv[0] + accv[1] + accv[2] + accv[3];
  }
  asm volatile("s_waitcnt lgkmcnt(0)" ::: "memory");   // wave-local fence

  // ---- Phase B (per-wave, 5 iters): w-pairs (h0,h1) per (m,hp,k) ----
  #pragma unroll
  for (int it = 0; it < 5; ++it) {
    int idx = it * 64 + lane;
    if (idx < 2 * 13 * KP) {
      int k  = idx % KP;
      int t  = idx / KP;         // 0..25
      int m  = m0 + (t & 1);
      int hp = t >> 1;           // 0..12
      float kx = KPQ(m, k * 3 + 0), ky = KPQ(m, k * 3 + 1), kz = KPQ(m, k * 3 + 2);
      int h0 = hp * 2;
      float dx0 = NBR(m, h0 * 3 + 0) - kx;
      float dy0 = NBR(m, h0 * 3 + 1) - ky;
      float dz0 = NBR(m, h0 * 3 + 2) - kz;
      float w0 = fmaxf(1.0f - sqrtf(dx0 * dx0 + dy0 * dy0 + dz0 * dz0) * (1.0f / 1.2f), 0.0f);
      float dx1 = NBR(m, h0 * 3 + 3) - kx;
      float dy1 = NBR(m, h0 * 3 + 4) - ky;
      float dz1 = NBR(m, h0 * 3 + 5) - kz;
      float w1 = fmaxf(1.0f - sqrtf(dx1 * dx1 + dy1 * dy1 + dz1 * dz1) * (1.0f / 1.2f), 0.0f);
      AW(m, hp, k) = pkrtz_u32(w0, w1);
    }
  }
  // ---- post-B block barrier: nbr/kp dead for ALL waves; sA may be written.
  // Raw s_barrier (no vmcnt drain) keeps window gathers in flight.
  asm volatile("s_waitcnt lgkmcnt(0)" ::: "memory");
  __builtin_amdgcn_s_barrier();
  asm volatile("" ::: "memory");

  // ---- Phase C (per-thread single row): 13-deep fp32 window; fdot2 ----
  {
    float acc0[KP], acc1[KP];
    #pragma unroll
    for (int k = 0; k < KP; ++k) { acc0[k] = 0.f; acc1[k] = 0.f; }

    #pragma unroll
    for (int p = 0; p < 13; ++p) {
      f32x2 v0 = win[(2 * p) % 13];
      f32x2 v1 = win[(2 * p + 1) % 13];
      if (2 * p + 13 < NB_H)
        win[(2 * p) % 13] = *(const f32x2*)(xb + voff[2 * p + 13]);
      if (2 * p + 14 < NB_H)
        win[(2 * p + 1) % 13] = *(const f32x2*)(xb + voff[2 * p + 14]);
      // pair_j = (x_h0[i0+j], x_h1[i0+j]) built directly from fp32 (RTN = old prep)
      unsigned int p0 = packh2(v0[0], v1[0]);
      unsigned int p1 = packh2(v0[1], v1[1]);

      unsigned int wr[KP];
      *(u32x4*)&wr[0] = *(const u32x4*)&AW(rowc, p, 0);
      *(u32x4*)&wr[4] = *(const u32x4*)&AW(rowc, p, 4);
      *(u32x2*)&wr[8] = *(const u32x2*)&AW(rowc, p, 8);

      #pragma unroll
      for (int k = 0; k < KP; ++k) {
        acc0[k] = fdot2u(wr[k], p0, acc0[k]);
        acc1[k] = fdot2u(wr[k], p1, acc1[k]);
      }
    }

    // swizzled frag store (verified R3): slot = kq*16+row;
    // half = slot*8 + j, XOR (kq<<3)^(qhi<<5); +qhi*512 frag parity
    const int kq  = (il & 15) >> 2;
    const int qhi = il >> 4;
    const int j2  = (2 * il) & 7;
    const int swz = (kq << 3) ^ (qhi << 5);
    const int hb  = (((kq * 16 + rowc) * 8 + j2) ^ swz) + qhi * 512;
    #pragma unroll
    for (int k = 0; k < KP; ++k)
      *(unsigned int*)(sA + k * 1024 + hb) = pkrtz_u32(acc0[k], acc1[k]);
  }

  // ---- bp depth-4 prefetch BEFORE the barrier (stays in flight across it) ----
  const int ct = wv;                                  // one 16-col tile per wave
  u16x8 pb[4];
  #pragma unroll
  for (int d = 0; d < 4; ++d)
    pb[d] = *(const u16x8*)(bp + (long)((ct * 20 + d) * 64 + lane) * 8);

  // ---- pre-GEMM block barrier: sA complete (raw, no vmcnt drain) ----
  asm volatile("s_waitcnt lgkmcnt(0)" ::: "memory");
  __builtin_amdgcn_s_barrier();
  asm volatile("" ::: "memory");

  // ---- GEMM: out[16][ct*16..+16] = A[16][640] @ B[640][16] (fp16 MFMA) ----
  {
    const int a0 = (lane * 8) ^ ((lane >> 4) << 3);   // halves within frag

    f32x4 acc = (f32x4){0.f, 0.f, 0.f, 0.f};

    #pragma unroll
    for (int ks = 0; ks < 20; ++ks) {
      f16x8 b = __builtin_bit_cast(f16x8, pb[ks & 3]);
      if (ks + 4 < 20)
        pb[ks & 3] = *(const u16x8*)(bp + (long)((ct * 20 + ks + 4) * 64 + lane) * 8);
      u16x8 au = *(const u16x8*)&sA[ks * 512 + (a0 ^ ((ks & 1) << 5))];
      f16x8 a = __builtin_bit_cast(f16x8, au);
      acc = __builtin_amdgcn_mfma_f32_16x16x32_f16(a, b, acc, 0, 0, 0);
    }

    // C/D layout: col = lane&15, row = (lane>>4)*4 + reg  [measured m89/m91]
    const int col   = lane & 15;
    const int rbase = (lane >> 4) * 4;
    #pragma unroll
    for (int r = 0; r < 4; ++r) {
      long row = row0 + rbase + r;
      __builtin_nontemporal_store(acc[r], &out[row * COUT + ct * 16 + col]);
    }
  }
}

extern "C" void kernel_launch(void* const* d_in, const int* in_sizes, int n_in,
                              void* d_out, int out_size, void* d_ws, size_t ws_size,
                              hipStream_t stream) {
  const float* q_pts = (const float*)d_in[0];
  const float* s_pts = (const float*)d_in[1];
  const float* x     = (const float*)d_in[2];
  const float* gen_W = (const float*)d_in[3];
  const float* gen_b = (const float*)d_in[4];
  const float* wts   = (const float*)d_in[5];
  const int*   inds  = (const int*)d_in[6];
  float* out = (float*)d_out;

  unsigned short* bp = (unsigned short*)d_ws;            // 81920 fp16 = 160 KB

  prep_kernel<<<PACK_BLOCKS, 256, 0, stream>>>(wts, bp);
  kpconv_fused<<<N_Q / BM, 512, 0, stream>>>(q_pts, s_pts, gen_W, gen_b,
                                             inds, x, bp, out);
}